// Round 3
// baseline (911.614 us; speedup 1.0000x reference)
//
#include <hip/hip_runtime.h>
#include <hip/hip_bf16.h>

#define BSZ   64
#define SEQL  100
#define DIM   512
#define L1P   101
#define NCOLS 6464     // BSZ*L1P
#define NROWS 6400     // BSZ*SEQL
#define D3    1536
#define MASKV -10000.0f
#define M0    16.0f    // fixed softmax reference: logits provably < ~10

// GRU partitioning: 4 independent sample-groups x 16 dim-blocks = 64 blocks.
#define SGRP  4
#define SPG   16
#define DBLK  16
#define DPB   32
#define GRU_BLOCKS (SGRP * DBLK)
#define SENT64 0x7FC07FC07FC07FC0ULL   // 4x bf16 NaN: unreachable as real h
#define INIT_N  409600                 // 6400*512*2B / 16B  (sentinel uint4s)
#define INIT_NP 410624                 // + 16 pad rows (zeroed)

typedef __attribute__((ext_vector_type(8))) short bf16x8;
typedef __attribute__((ext_vector_type(4))) float f32x4;

__device__ __forceinline__ float sigm(float x)  { return 1.f / (1.f + __expf(-x)); }
__device__ __forceinline__ float ftanh(float x) { float e = __expf(2.f * x); return 1.f - 2.f / (e + 1.f); }
__device__ __forceinline__ ushort f2bf(float x) {
    __hip_bfloat16 b = __float2bfloat16(x);
    return *(ushort*)&b;
}

// ---------------- K0: init workspace ------------------------------------------
__global__ void init_ws(float* s_glob, float* acc, uint4* prec_all)
{
    int t = blockIdx.x * 256 + threadIdx.x;     // grid 1604*256 = 410624
    if (t < INIT_N) {
        uint4 s; s.x = 0x7FC07FC0u; s.y = 0x7FC07FC0u; s.z = 0x7FC07FC0u; s.w = 0x7FC07FC0u;
        prec_all[t] = s;
    } else if (t < INIT_NP) {
        uint4 z; z.x = 0u; z.y = 0u; z.z = 0u; z.w = 0u;
        prec_all[t] = z;
    }
    if (t < NROWS) s_glob[t] = 0.f;
    if (t < 2) acc[t] = 0.f;
}

// ---------------- K1: gather score16[k][:] = bf16(id_emb[ids[k]][:]) ----------
__global__ void gather_embs(const int* __restrict__ ids, const float* __restrict__ emb,
                            ushort* __restrict__ score16)
{
    int idx = blockIdx.x * 256 + threadIdx.x;   // 6464*128
    int row = idx >> 7, c4 = idx & 127;
    int id = ids[row];
    float4 v = *(const float4*)&emb[(size_t)id * DIM + c4 * 4];
    ushort4 u;
    u.x = f2bf(v.x); u.y = f2bf(v.y); u.z = f2bf(v.z); u.w = f2bf(v.w);
    *(ushort4*)&score16[(size_t)row * DIM + c4 * 4] = u;
}

// ---------------- K2: debias + col_valid --------------------------------------
__global__ void aux_kernel(const int* __restrict__ ids, const float* __restrict__ pop,
                           const int* __restrict__ lmask,
                           float* __restrict__ debias, int* __restrict__ colv)
{
    int k = blockIdx.x * 256 + threadIdx.x;
    if (k >= NCOLS) return;
    int id = ids[k];
    debias[k] = __logf(pop[id]);
    int j = k % L1P;
    colv[k] = (j == SEQL) ? 1 : lmask[(k / L1P) * SEQL + j];
}

// ---------------- K3: rejm[i][k] = fused mask code ----------------------------
__global__ void build_reject(const int* __restrict__ ids, const int* __restrict__ colv,
                             unsigned char* __restrict__ rejm)
{
    __shared__ int s_ids[L1P];
    int i = blockIdx.y;
    int tid = threadIdx.x;
    if (tid < L1P) s_ids[tid] = ids[i * L1P + tid];
    __syncthreads();
    int k = blockIdx.x * 256 + tid;
    if (k >= NCOLS) return;
    int myid = ids[k];
    int rej = 0;
    for (int j = 0; j < L1P; ++j) rej |= (myid == s_ids[j]);
    unsigned char code = (colv[k] == 0) ? 1 : (rej ? 2 : 0);
    rejm[(size_t)i * NCOLS + k] = code;
}

// ---------------- K4: tiled transpose WT[c][k] = bf16(W[k][c]) ----------------
__global__ __launch_bounds__(256) void wt_tile(const float* __restrict__ W,
                                               ushort* __restrict__ WT)
{
    __shared__ float tile[64][65];
    int c0 = blockIdx.x * 64, k0 = blockIdx.y * 64;
    int tx = threadIdx.x & 63, ty = threadIdx.x >> 6;
    for (int r = ty; r < 64; r += 4)
        tile[r][tx] = W[(size_t)(k0 + r) * D3 + c0 + tx];
    __syncthreads();
    for (int r = ty; r < 64; r += 4)
        WT[(size_t)(c0 + r) * DIM + k0 + tx] = f2bf(tile[tx][r]);
}

// ---------------- K5: gates = x @ W_ih + b_ih, LDS-staged + A-prefetch --------
// 240 blocks (24 col-chunks x 10 row-groups). B-slab = 64 cols x 512 K (64 KB
// contiguous in WIT) staged ONCE via global_load_lds with the K7-verified XOR
// swizzle; 10 row-tiles of 64 rows processed with double-buffered A-fragments.
__global__ __launch_bounds__(256, 1) void gates_mfma(
    const ushort* __restrict__ score16, const ushort* __restrict__ WIT,
    const float* __restrict__ b_ih, float* __restrict__ gates)
{
    __shared__ ushort Bs[64 * 512];             // 64 KB
    int n0 = blockIdx.x * 64;
    int rowbase = blockIdx.y * 640;
    int tid = threadIdx.x;
    int w = tid >> 6, lane = tid & 63, l15 = lane & 15, quad = lane >> 4;

    {   // stage B slab, inverse-swizzled source, linear LDS dest
        const char* slab = (const char*)(WIT + (size_t)n0 * DIM);
#pragma unroll
        for (int k = 0; k < 16; ++k) {
            int o  = k * 4096 + w * 1024 + lane * 16;
            int so = o ^ (((o >> 10) & 15) << 4);
            __builtin_amdgcn_global_load_lds(
                (const __attribute__((address_space(1))) void*)(slab + so),
                (__attribute__((address_space(3))) void*)((char*)Bs + k * 4096 + w * 1024),
                16, 0, 0);
        }
    }
    float bi[4];
#pragma unroll
    for (int nt = 0; nt < 4; ++nt) bi[nt] = b_ih[n0 + nt * 16 + l15];

    asm volatile("s_waitcnt vmcnt(0)" ::: "memory");
    __syncthreads();

    int key = l15 << 4;
    bf16x8 afA[16], afB[16];

    auto load_af = [&](bf16x8 (&dst)[16], int rt) {
        int r = rowbase + rt * 64 + w * 16 + l15;
        int i = r / SEQL, j = r - i * SEQL;
        const ushort* ap = score16 + (size_t)(i * L1P + j) * DIM + quad * 8;
#pragma unroll
        for (int c = 0; c < 16; ++c) dst[c] = *(const bf16x8*)(ap + c * 32);
    };
    auto do_tile = [&](const bf16x8 (&af)[16], int rt) {
        f32x4 acc[4] = {{0,0,0,0},{0,0,0,0},{0,0,0,0},{0,0,0,0}};
        const char* bt = (const char*)Bs;
#pragma unroll
        for (int c = 0; c < 16; ++c) {
#pragma unroll
            for (int nt = 0; nt < 4; ++nt) {
                int a = (nt * 16 + l15) * 1024 + ((c * 64 + quad * 16) ^ key);
                bf16x8 bb = *(const bf16x8*)(bt + a);
                acc[nt] = __builtin_amdgcn_mfma_f32_16x16x32_bf16(af[c], bb, acc[nt], 0, 0, 0);
            }
        }
#pragma unroll
        for (int nt = 0; nt < 4; ++nt) {
#pragma unroll
            for (int p = 0; p < 4; ++p) {
                int rr = rowbase + rt * 64 + w * 16 + quad * 4 + p;
                gates[(size_t)rr * D3 + n0 + nt * 16 + l15] = acc[nt][p] + bi[nt];
            }
        }
    };

    load_af(afA, 0);
#pragma unroll
    for (int rp = 0; rp < 5; ++rp) {
        load_af(afB, rp * 2 + 1);
        do_tile(afA, rp * 2);
        if (rp < 4) load_af(afA, rp * 2 + 2);
        do_tile(afB, rp * 2 + 1);
    }
}

// ---------------- K6: sentinel-polled MFMA GRU, 1 barrier/step ----------------
// vs r2: hpub LDS + 2nd barrier removed. wk0 lanes shfl-pack the u64 (dims
// l15..l15+3 of a sample live in adjacent lanes of one quad) and publish
// directly inside the epilogue -> store lands earlier, wk1 waves go straight
// to the next poll. red is t-parity double-buffered: without bar2, wk1's
// step-t+1 partial write could race wk0's step-t read (bar2 used to order
// this); parity buffers give a 2-step reuse margin secured by the publish->
// poll dependency chain.
__global__ __launch_bounds__(256) void gru_mfma(
    const ushort* __restrict__ WT,      // [1536][512] bf16 = W_hh^T
    const float* __restrict__ b_hh,
    const float* __restrict__ gates,    // [6400][1536] f32 (includes b_ih)
    ushort* __restrict__ prec16)        // [(6400+16)][512] bf16 per-step h
{
    __shared__ float red[2][2][3][256]; // [t&1][wc][gate][lane*4+p]

    int b = blockIdx.x;
    int sg = b >> 4, db = b & 15;
    int s0 = sg * SPG, d0 = db * DPB;
    int tid = threadIdx.x;
    int w = tid >> 6, lane = tid & 63, l15 = lane & 15, quad = lane >> 4;
    int wc = w & 1, wk = w >> 1;
    int kb = wk * 8;

    bf16x8 wreg[3][8];
#pragma unroll
    for (int g = 0; g < 3; ++g)
#pragma unroll
        for (int cc = 0; cc < 8; ++cc)
            wreg[g][cc] = *(const bf16x8*)(WT
                + (size_t)(g * 512 + d0 + wc * 16 + l15) * DIM
                + (kb + cc) * 32 + quad * 8);

    int d = d0 + wc * 16 + l15;
    float bhr = b_hh[d], bhz = b_hh[512 + d], bhn = b_hh[1024 + d];
    float hprev[4] = {0.f, 0.f, 0.f, 0.f};

    for (int t = 0; t < SEQL; ++t) {
        int tp = t & 1;
        float xr[4], xz[4], xn[4];
        if (wk == 0) {
#pragma unroll
            for (int p = 0; p < 4; ++p) {
                int ss = s0 + quad * 4 + p;
                const float* gx = gates + ((size_t)ss * SEQL + t) * D3;
                xr[p] = gx[d]; xz[p] = gx[512 + d]; xn[p] = gx[1024 + d];
            }
        }
        f32x4 acc[3] = {{0,0,0,0},{0,0,0,0},{0,0,0,0}};
        if (t > 0) {
            const ushort* ap = prec16
                + ((size_t)(s0 + l15) * SEQL + (t - 1)) * DIM + quad * 8;
            unsigned long long v[16];
            bool again = true;
            while (again) {
#pragma unroll
                for (int u = 0; u < 16; ++u) {
                    const unsigned long long* p64 = (const unsigned long long*)
                        (ap + (kb + (u >> 1)) * 32 + (u & 1) * 4);
                    v[u] = __hip_atomic_load(p64, __ATOMIC_RELAXED,
                                             __HIP_MEMORY_SCOPE_AGENT);
                }
                unsigned long long bad = 0ull;
#pragma unroll
                for (int u = 0; u < 16; ++u) {
                    unsigned long long x = v[u] ^ SENT64;
                    bad |= (x - 0x0001000100010001ULL) & ~x & 0x8000800080008000ULL;
                }
                again = (bad != 0ull);
                if (again) __builtin_amdgcn_s_sleep(1);
            }
#pragma unroll
            for (int cc = 0; cc < 8; ++cc) {
                union { unsigned long long q[2]; bf16x8 h; } af;
                af.q[0] = v[2 * cc]; af.q[1] = v[2 * cc + 1];
#pragma unroll
                for (int g = 0; g < 3; ++g)
                    acc[g] = __builtin_amdgcn_mfma_f32_16x16x32_bf16(
                        af.h, wreg[g][cc], acc[g], 0, 0, 0);
            }
        }
        if (wk == 1) {
#pragma unroll
            for (int g = 0; g < 3; ++g)
                *(f32x4*)&red[tp][wc][g][lane * 4] = acc[g];
        }
        __syncthreads();
        if (wk == 0) {
#pragma unroll
            for (int p = 0; p < 4; ++p) {
                float a0 = acc[0][p] + red[tp][wc][0][lane * 4 + p];
                float a1 = acc[1][p] + red[tp][wc][1][lane * 4 + p];
                float a2 = acc[2][p] + red[tp][wc][2][lane * 4 + p];
                float r = sigm(xr[p] + a0 + bhr);
                float z = sigm(xz[p] + a1 + bhz);
                float n = ftanh(xn[p] + r * (a2 + bhn));
                float hnew = (1.f - z) * n + z * hprev[p];
                hprev[p] = hnew;
                // shfl-pack u64: dims l15..l15+3 of sample (quad*4+p) sit in
                // adjacent lanes of this quad (lane^1 flips l15 bit0, ^2 bit1)
                unsigned b16 = f2bf(hnew);
                unsigned lo = b16 | (((unsigned)__shfl_xor((int)b16, 1)) << 16);
                unsigned long long hi = (unsigned)__shfl_xor((int)lo, 2);
                unsigned long long vv = (unsigned long long)lo | (hi << 32);
                if ((l15 & 3) == 0) {
                    unsigned long long* dst = (unsigned long long*)
                        (prec16 + ((size_t)(s0 + quad * 4 + p) * SEQL + t) * DIM
                         + d0 + wc * 16 + l15);
                    __hip_atomic_store(dst, vv, __ATOMIC_RELAXED,
                                       __HIP_MEMORY_SCOPE_AGENT);
                }
            }
        }
    }
}

// ---------------- K7: pipelined LDS-staged MFMA logits (unchanged r2) ---------
__global__ __launch_bounds__(256, 2) void logits_mfma(
    const ushort* __restrict__ prec16, const ushort* __restrict__ score16,
    const float* __restrict__ debias, const unsigned char* __restrict__ rejm,
    float* __restrict__ s_glob, float* __restrict__ label_glob)
{
    __shared__ ushort Bt[2][16 * 512];          // 2 x 16 KB
    __shared__ float dbs[816];
    __shared__ unsigned char rjs[816];

    int bi = blockIdx.x;
    int i  = bi >> 3;
    int cs = (bi >> 1) & 3;
    int h  = bi & 1;
    int tile0  = cs * 101 + h * 51;             // global column-tile index base
    int ntiles = 51 - h;                        // 51 or 50
    int tid  = threadIdx.x;
    int lane = tid & 63;
    int w    = tid >> 6;
    int l15  = lane & 15, quad = lane >> 4;

    bf16x8 afrag[2][16];
    bool live1 = (w < 3);                       // row-tile 7 skipped
    {
        int r0 = i * SEQL + (2 * w) * 16 + l15;
        const ushort* ap = prec16 + (size_t)r0 * DIM + quad * 8;
#pragma unroll
        for (int c = 0; c < 16; ++c) afrag[0][c] = *(const bf16x8*)(ap + c * 32);
    }
    if (live1) {
        int r1 = i * SEQL + (2 * w + 1) * 16 + l15;
        const ushort* ap = prec16 + (size_t)r1 * DIM + quad * 8;
#pragma unroll
        for (int c = 0; c < 16; ++c) afrag[1][c] = *(const bf16x8*)(ap + c * 32);
    }

    int ncols = ntiles * 16;
    int nb0 = tile0 * 16;
    for (int idx = tid; idx < ncols; idx += 256) {
        dbs[idx] = debias[nb0 + idx];
        rjs[idx] = rejm[(size_t)i * NCOLS + nb0 + idx];
    }

    auto stage = [&](int buf, int st) {
        const char* slab = (const char*)(score16 + (size_t)(tile0 + st) * 16 * DIM);
#pragma unroll
        for (int k = 0; k < 4; ++k) {
            int o  = k * 4096 + w * 1024 + lane * 16;
            int so = o ^ (((o >> 10) & 15) << 4);
            __builtin_amdgcn_global_load_lds(
                (const __attribute__((address_space(1))) void*)(slab + so),
                (__attribute__((address_space(3))) void*)((char*)&Bt[buf][0] + k * 4096 + w * 1024),
                16, 0, 0);
        }
    };

    stage(0, 0);
    asm volatile("s_waitcnt vmcnt(0)" ::: "memory");
    __syncthreads();

    float srun0[4] = {0.f, 0.f, 0.f, 0.f};
    float srun1[4] = {0.f, 0.f, 0.f, 0.f};
    int colb = l15 * 1024;
    int q16  = quad * 16;
    int key  = l15 << 4;

    for (int st = 0; st < ntiles; ++st) {
        int cur = st & 1;
        if (st + 1 < ntiles) stage(cur ^ 1, st + 1);

        const char* bt = (const char*)&Bt[cur][0];
        f32x4 acc0[2] = {{0,0,0,0},{0,0,0,0}};
        f32x4 acc1[2] = {{0,0,0,0},{0,0,0,0}};
#pragma unroll
        for (int c = 0; c < 16; ++c) {
            int a = colb + ((c * 64 + q16) ^ key);
            bf16x8 b = *(const bf16x8*)(bt + a);
            acc0[c & 1] = __builtin_amdgcn_mfma_f32_16x16x32_bf16(afrag[0][c], b, acc0[c & 1], 0, 0, 0);
            if (live1)
                acc1[c & 1] = __builtin_amdgcn_mfma_f32_16x16x32_bf16(afrag[1][c], b, acc1[c & 1], 0, 0, 0);
        }

        int mi = st * 16 + l15;
        int n  = nb0 + mi;
        float db = dbs[mi];
        int   mc = rjs[mi];
        int   jj = n - i * L1P - 1;
        {
            int rowb = (2 * w) * 16 + quad * 4;
#pragma unroll
            for (int p = 0; p < 4; ++p) {
                int j = rowb + p;
                float l = acc0[0][p] + acc0[1][p] - db;
                bool is_t = (j == jj);
                bool msk = (mc == 1) || (mc == 2 && !is_t);
                l = msk ? MASKV : l;
                if (is_t && j < SEQL) label_glob[i * SEQL + j] = l;
                if (j < SEQL) srun0[p] += __expf(l - M0);
            }
        }
        if (live1) {
            int rowb = (2 * w + 1) * 16 + quad * 4;
#pragma unroll
            for (int p = 0; p < 4; ++p) {
                int j = rowb + p;
                float l = acc1[0][p] + acc1[1][p] - db;
                bool is_t = (j == jj);
                bool msk = (mc == 1) || (mc == 2 && !is_t);
                l = msk ? MASKV : l;
                if (is_t && j < SEQL) label_glob[i * SEQL + j] = l;
                if (j < SEQL) srun1[p] += __expf(l - M0);
            }
        }
        __syncthreads();
    }

#pragma unroll
    for (int p = 0; p < 4; ++p) {
        float s = srun0[p];
        s += __shfl_xor(s, 1); s += __shfl_xor(s, 2);
        s += __shfl_xor(s, 4); s += __shfl_xor(s, 8);
        if (l15 == 0) {
            int j = (2 * w) * 16 + quad * 4 + p;
            if (j < SEQL) atomicAdd(&s_glob[i * SEQL + j], s);
        }
    }
    if (live1) {
#pragma unroll
        for (int p = 0; p < 4; ++p) {
            float s = srun1[p];
            s += __shfl_xor(s, 1); s += __shfl_xor(s, 2);
            s += __shfl_xor(s, 4); s += __shfl_xor(s, 8);
            if (l15 == 0) {
                int j = (2 * w + 1) * 16 + quad * 4 + p;
                if (j < SEQL) atomicAdd(&s_glob[i * SEQL + j], s);
            }
        }
    }
}

// ---------------- K8: per-row NLL + weighted sum ------------------------------
__global__ void nll_reduce(const float* __restrict__ s_glob, const float* __restrict__ label_glob,
                           const int* __restrict__ lmask, float* __restrict__ acc)
{
    int r = blockIdx.x * 256 + threadIdx.x;
    float v = 0.f, wt = 0.f;
    if (r < NROWS) {
        wt = (lmask[r] != 0) ? 1.f : 0.f;
        v  = (M0 + __logf(s_glob[r]) - label_glob[r]) * wt;
    }
#pragma unroll
    for (int o = 32; o; o >>= 1) { v += __shfl_down(v, o); wt += __shfl_down(wt, o); }
    if ((threadIdx.x & 63) == 0) { atomicAdd(&acc[0], v); atomicAdd(&acc[1], wt); }
}

// ---------------- K9: finalize ------------------------------------------------
__global__ void finalize(const float* __restrict__ acc, float* __restrict__ out)
{
    out[0] = acc[0] / fmaxf(acc[1], 1.f);
}

extern "C" void kernel_launch(void* const* d_in, const int* in_sizes, int n_in,
                              void* d_out, int out_size, void* d_ws, size_t ws_size,
                              hipStream_t stream)
{
    const int*   ids   = (const int*)d_in[0];
    const int*   lmask = (const int*)d_in[1];
    const float* pop   = (const float*)d_in[2];
    const float* emb   = (const float*)d_in[3];
    const float* W_ih  = (const float*)d_in[4];
    const float* W_hh  = (const float*)d_in[5];
    const float* b_ih  = (const float*)d_in[6];
    const float* b_hh  = (const float*)d_in[7];
    float* out = (float*)d_out;

    // workspace layout (~57 MB)
    ushort* score16 = (ushort*)d_ws;                               // 6464*512 bf16
    ushort* prec16  = score16 + (size_t)NCOLS * DIM;               // 6416*512 bf16 (incl pad)
    ushort* WT      = prec16 + (size_t)(NROWS + 16) * DIM;         // 1536*512 bf16 (W_hh^T)
    ushort* WIT     = WT + (size_t)D3 * DIM;                       // 1536*512 bf16 (W_ih^T)
    float*  debias  = (float*)(WIT + (size_t)D3 * DIM);            // 6464 f32
    int*    colv    = (int*)(debias + NCOLS);                      // 6464 i32
    unsigned char* rejm = (unsigned char*)(colv + NCOLS);          // 64*6464 u8
    float*  gates   = (float*)(rejm + (size_t)BSZ * NCOLS + 64);   // 6400*1536 f32
    float*  s_glob  = gates + (size_t)NROWS * D3;                  // 6400 f32
    float*  label_g = s_glob + NROWS;                              // 6400 f32
    float*  acc     = label_g + NROWS;                             // 2 f32

    init_ws<<<INIT_NP / 256, 256, 0, stream>>>(s_glob, acc, (uint4*)prec16);
    gather_embs<<<(NCOLS * 128) / 256, 256, 0, stream>>>(ids, emb, score16);
    aux_kernel<<<(NCOLS + 255) / 256, 256, 0, stream>>>(ids, pop, lmask, debias, colv);
    build_reject<<<dim3((NCOLS + 255) / 256, BSZ), 256, 0, stream>>>(ids, colv, rejm);
    wt_tile<<<dim3(24, 8), 256, 0, stream>>>(W_hh, WT);
    wt_tile<<<dim3(24, 8), 256, 0, stream>>>(W_ih, WIT);
    gates_mfma<<<dim3(24, 10), 256, 0, stream>>>(score16, WIT, b_ih, gates);
    gru_mfma<<<GRU_BLOCKS, 256, 0, stream>>>(WT, b_hh, gates, prec16);
    logits_mfma<<<BSZ * 8, 256, 0, stream>>>(prec16, score16, debias, rejm, s_glob, label_g);
    nll_reduce<<<(NROWS + 255) / 256, 256, 0, stream>>>(s_glob, label_g, lmask, acc);
    finalize<<<1, 1, 0, stream>>>(acc, out);
}

// Round 5
// 773.090 us; speedup vs baseline: 1.1792x; 1.1792x over previous
//
#include <hip/hip_runtime.h>
#include <hip/hip_bf16.h>

#define BSZ   64
#define SEQL  100
#define DIM   512
#define L1P   101
#define NCOLS 6464     // BSZ*L1P
#define NROWS 6400     // BSZ*SEQL
#define D3    1536
#define MASKV -10000.0f
#define M0    16.0f    // fixed softmax reference: logits provably < ~10

// GRU partitioning: 4 independent sample-groups x 16 dim-blocks = 64 blocks.
#define SGRP  4
#define SPG   16
#define DBLK  16
#define DPB   32
#define GRU_BLOCKS (SGRP * DBLK)
#define SENT64 0x7FC07FC07FC07FC0ULL   // 4x bf16 NaN: unreachable as real h
#define INIT_N  409600                 // 6400*512*2B / 16B  (sentinel uint4s)
#define INIT_NP 410624                 // + 16 pad rows (zeroed)

// fused prologue block ranges (order = rough dispatch priority: long first)
#define PB_GATHER0 0
#define PB_GATHERN 3232
#define PB_REJ0    (PB_GATHER0 + PB_GATHERN)    // 3232
#define PB_REJN    1664                         // 26 col-blocks x 64 samples
#define PB_INIT0   (PB_REJ0 + PB_REJN)          // 4896
#define PB_INITN   1604
#define PB_WT0     (PB_INIT0 + PB_INITN)        // 6500
#define PB_WTN     384                          // 192 x {W_hh, W_ih}
#define PB_AUX0    (PB_WT0 + PB_WTN)            // 6884
#define PB_AUXN    26
#define PB_TOTAL   (PB_AUX0 + PB_AUXN)          // 6910

typedef __attribute__((ext_vector_type(8))) short bf16x8;
typedef __attribute__((ext_vector_type(4))) float f32x4;

__device__ __forceinline__ float sigm(float x)  { return 1.f / (1.f + __expf(-x)); }
__device__ __forceinline__ float ftanh(float x) { float e = __expf(2.f * x); return 1.f - 2.f / (e + 1.f); }
__device__ __forceinline__ ushort f2bf(float x) {
    __hip_bfloat16 b = __float2bfloat16(x);
    return *(ushort*)&b;
}

// ---------------- K0: fused prologue ------------------------------------------
// One kernel, range-dispatched: gather | reject | init | wt-transpose x2 | aux.
// All paths independent (reject reads lmask directly, no colv dependency), so
// the latency-bound gather co-resides with the ALU-bound reject and the
// BW-bound sentinel init instead of serializing across 6 launches.
__global__ __launch_bounds__(256) void prologue(
    const int* __restrict__ ids, const int* __restrict__ lmask,
    const float* __restrict__ pop, const float* __restrict__ emb,
    const float* __restrict__ W_hh, const float* __restrict__ W_ih,
    ushort* __restrict__ score16, uint4* __restrict__ prec_all,
    ushort* __restrict__ WT, ushort* __restrict__ WIT,
    float* __restrict__ debias, unsigned char* __restrict__ rejm,
    float* __restrict__ s_glob, float* __restrict__ acc)
{
    __shared__ union {
        float tile[64][65];
        int   s_ids[L1P];
    } sm;
    int bid = blockIdx.x;
    int tid = threadIdx.x;

    if (bid < PB_REJ0) {                        // ---- gather_embs ----
        int idx = bid * 256 + tid;              // 6464*128
        int row = idx >> 7, c4 = idx & 127;
        int id = ids[row];
        float4 v = *(const float4*)&emb[(size_t)id * DIM + c4 * 4];
        ushort4 u;
        u.x = f2bf(v.x); u.y = f2bf(v.y); u.z = f2bf(v.z); u.w = f2bf(v.w);
        *(ushort4*)&score16[(size_t)row * DIM + c4 * 4] = u;
    } else if (bid < PB_INIT0) {                // ---- build_reject ----
        int rb = bid - PB_REJ0;
        int i  = rb / 26, kb = rb % 26;
        if (tid < L1P) sm.s_ids[tid] = ids[i * L1P + tid];
        __syncthreads();
        int k = kb * 256 + tid;
        if (k >= NCOLS) return;
        int myid = ids[k];
        int rej = 0;
        for (int j = 0; j < L1P; ++j) rej |= (myid == sm.s_ids[j]);
        int j = k % L1P;
        int cv = (j == SEQL) ? 1 : lmask[(k / L1P) * SEQL + j];
        rejm[(size_t)i * NCOLS + k] = (cv == 0) ? 1 : (rej ? 2 : 0);
    } else if (bid < PB_WT0) {                  // ---- init_ws ----
        int t = (bid - PB_INIT0) * 256 + tid;   // < 410624
        if (t < INIT_N) {
            uint4 s; s.x = 0x7FC07FC0u; s.y = 0x7FC07FC0u; s.z = 0x7FC07FC0u; s.w = 0x7FC07FC0u;
            prec_all[t] = s;
        } else {
            uint4 z; z.x = 0u; z.y = 0u; z.z = 0u; z.w = 0u;
            prec_all[t] = z;
        }
        if (t < NROWS) s_glob[t] = 0.f;
        if (t < 2) acc[t] = 0.f;
    } else if (bid < PB_AUX0) {                 // ---- wt_tile x2 ----
        int wb = bid - PB_WT0;
        int which = wb / 192, r = wb % 192;
        const float* W = which ? W_ih : W_hh;
        ushort* WTd    = which ? WIT  : WT;
        int c0 = (r % 24) * 64, k0 = (r / 24) * 64;
        int tx = tid & 63, ty = tid >> 6;
        for (int rr = ty; rr < 64; rr += 4)
            sm.tile[rr][tx] = W[(size_t)(k0 + rr) * D3 + c0 + tx];
        __syncthreads();
        for (int rr = ty; rr < 64; rr += 4)
            WTd[(size_t)(c0 + rr) * DIM + k0 + tx] = f2bf(sm.tile[tx][rr]);
    } else {                                    // ---- aux (debias) ----
        int k = (bid - PB_AUX0) * 256 + tid;
        if (k >= NCOLS) return;
        debias[k] = __logf(pop[ids[k]]);
    }
}

// ---------------- K5: gates = x @ W_ih + b_ih, LDS-staged + A-prefetch --------
// (r3 version, kept: part of the tail improvement)
__global__ __launch_bounds__(256, 1) void gates_mfma(
    const ushort* __restrict__ score16, const ushort* __restrict__ WIT,
    const float* __restrict__ b_ih, float* __restrict__ gates)
{
    __shared__ ushort Bs[64 * 512];             // 64 KB
    int n0 = blockIdx.x * 64;
    int rowbase = blockIdx.y * 640;
    int tid = threadIdx.x;
    int w = tid >> 6, lane = tid & 63, l15 = lane & 15, quad = lane >> 4;

    {   // stage B slab, inverse-swizzled source, linear LDS dest
        const char* slab = (const char*)(WIT + (size_t)n0 * DIM);
#pragma unroll
        for (int k = 0; k < 16; ++k) {
            int o  = k * 4096 + w * 1024 + lane * 16;
            int so = o ^ (((o >> 10) & 15) << 4);
            __builtin_amdgcn_global_load_lds(
                (const __attribute__((address_space(1))) void*)(slab + so),
                (__attribute__((address_space(3))) void*)((char*)Bs + k * 4096 + w * 1024),
                16, 0, 0);
        }
    }
    float bi[4];
#pragma unroll
    for (int nt = 0; nt < 4; ++nt) bi[nt] = b_ih[n0 + nt * 16 + l15];

    asm volatile("s_waitcnt vmcnt(0)" ::: "memory");
    __syncthreads();

    int key = l15 << 4;
    bf16x8 afA[16], afB[16];

    auto load_af = [&](bf16x8 (&dst)[16], int rt) {
        int r = rowbase + rt * 64 + w * 16 + l15;
        int i = r / SEQL, j = r - i * SEQL;
        const ushort* ap = score16 + (size_t)(i * L1P + j) * DIM + quad * 8;
#pragma unroll
        for (int c = 0; c < 16; ++c) dst[c] = *(const bf16x8*)(ap + c * 32);
    };
    auto do_tile = [&](const bf16x8 (&af)[16], int rt) {
        f32x4 acc[4] = {{0,0,0,0},{0,0,0,0},{0,0,0,0},{0,0,0,0}};
        const char* bt = (const char*)Bs;
#pragma unroll
        for (int c = 0; c < 16; ++c) {
#pragma unroll
            for (int nt = 0; nt < 4; ++nt) {
                int a = (nt * 16 + l15) * 1024 + ((c * 64 + quad * 16) ^ key);
                bf16x8 bb = *(const bf16x8*)(bt + a);
                acc[nt] = __builtin_amdgcn_mfma_f32_16x16x32_bf16(af[c], bb, acc[nt], 0, 0, 0);
            }
        }
#pragma unroll
        for (int nt = 0; nt < 4; ++nt) {
#pragma unroll
            for (int p = 0; p < 4; ++p) {
                int rr = rowbase + rt * 64 + w * 16 + quad * 4 + p;
                gates[(size_t)rr * D3 + n0 + nt * 16 + l15] = acc[nt][p] + bi[nt];
            }
        }
    };

    load_af(afA, 0);
#pragma unroll
    for (int rp = 0; rp < 5; ++rp) {
        load_af(afB, rp * 2 + 1);
        do_tile(afA, rp * 2);
        if (rp < 4) load_af(afA, rp * 2 + 2);
        do_tile(afB, rp * 2 + 1);
    }
}

// ---------------- K6: sentinel-polled MFMA GRU (exact r2 revert) --------------
// r3 post-mortem: moving the publish into wk0's epilogue behind a shfl chain
// delayed it and cost +127 us. The r2 structure (hpub bounce + barrier2 + burst
// publish by 128 dedicated threads) is the measured best: 384 us.
__global__ __launch_bounds__(256) void gru_mfma(
    const ushort* __restrict__ WT,      // [1536][512] bf16 = W_hh^T
    const float* __restrict__ b_hh,
    const float* __restrict__ gates,    // [6400][1536] f32 (includes b_ih)
    ushort* __restrict__ prec16)        // [(6400+16)][512] bf16 per-step h
{
    __shared__ float  red[2][3][256];   // wk=1 partial C tiles
    __shared__ ushort hpub[16][32];     // transpose bounce for u64 publish

    int b = blockIdx.x;
    int sg = b >> 4, db = b & 15;
    int s0 = sg * SPG, d0 = db * DPB;
    int tid = threadIdx.x;
    int w = tid >> 6, lane = tid & 63, l15 = lane & 15, quad = lane >> 4;
    int wc = w & 1, wk = w >> 1;
    int kb = wk * 8;

    bf16x8 wreg[3][8];
#pragma unroll
    for (int g = 0; g < 3; ++g)
#pragma unroll
        for (int cc = 0; cc < 8; ++cc)
            wreg[g][cc] = *(const bf16x8*)(WT
                + (size_t)(g * 512 + d0 + wc * 16 + l15) * DIM
                + (kb + cc) * 32 + quad * 8);

    int d = d0 + wc * 16 + l15;
    float bhr = b_hh[d], bhz = b_hh[512 + d], bhn = b_hh[1024 + d];
    float hprev[4] = {0.f, 0.f, 0.f, 0.f};

    for (int t = 0; t < SEQL; ++t) {
        float xr[4], xz[4], xn[4];
        if (wk == 0) {
#pragma unroll
            for (int p = 0; p < 4; ++p) {
                int ss = s0 + quad * 4 + p;
                const float* gx = gates + ((size_t)ss * SEQL + t) * D3;
                xr[p] = gx[d]; xz[p] = gx[512 + d]; xn[p] = gx[1024 + d];
            }
        }
        f32x4 acc[3] = {{0,0,0,0},{0,0,0,0},{0,0,0,0}};
        if (t > 0) {
            const ushort* ap = prec16
                + ((size_t)(s0 + l15) * SEQL + (t - 1)) * DIM + quad * 8;
            unsigned long long v[16];
            bool again = true;
            while (again) {
#pragma unroll
                for (int u = 0; u < 16; ++u) {
                    const unsigned long long* p64 = (const unsigned long long*)
                        (ap + (kb + (u >> 1)) * 32 + (u & 1) * 4);
                    v[u] = __hip_atomic_load(p64, __ATOMIC_RELAXED,
                                             __HIP_MEMORY_SCOPE_AGENT);
                }
                unsigned long long bad = 0ull;
#pragma unroll
                for (int u = 0; u < 16; ++u) {
                    unsigned long long x = v[u] ^ SENT64;
                    bad |= (x - 0x0001000100010001ULL) & ~x & 0x8000800080008000ULL;
                }
                again = (bad != 0ull);
                if (again) __builtin_amdgcn_s_sleep(1);
            }
#pragma unroll
            for (int cc = 0; cc < 8; ++cc) {
                union { unsigned long long q[2]; bf16x8 h; } af;
                af.q[0] = v[2 * cc]; af.q[1] = v[2 * cc + 1];
#pragma unroll
                for (int g = 0; g < 3; ++g)
                    acc[g] = __builtin_amdgcn_mfma_f32_16x16x32_bf16(
                        af.h, wreg[g][cc], acc[g], 0, 0, 0);
            }
        }
        if (wk == 1) {
#pragma unroll
            for (int g = 0; g < 3; ++g)
                *(f32x4*)&red[wc][g][lane * 4] = acc[g];
        }
        __syncthreads();
        if (wk == 0) {
#pragma unroll
            for (int p = 0; p < 4; ++p) {
                float a0 = acc[0][p] + red[wc][0][lane * 4 + p];
                float a1 = acc[1][p] + red[wc][1][lane * 4 + p];
                float a2 = acc[2][p] + red[wc][2][lane * 4 + p];
                float r = sigm(xr[p] + a0 + bhr);
                float z = sigm(xz[p] + a1 + bhz);
                float n = ftanh(xn[p] + r * (a2 + bhn));
                float hnew = (1.f - z) * n + z * hprev[p];
                hprev[p] = hnew;
                hpub[quad * 4 + p][wc * 16 + l15] = f2bf(hnew);
            }
        }
        __syncthreads();
        if (tid >= 128) {
            int pt = tid - 128;
            int ss = pt >> 3, gq = pt & 7;
            unsigned long long vv =
                 (unsigned long long)hpub[ss][gq * 4 + 0]
               | ((unsigned long long)hpub[ss][gq * 4 + 1] << 16)
               | ((unsigned long long)hpub[ss][gq * 4 + 2] << 32)
               | ((unsigned long long)hpub[ss][gq * 4 + 3] << 48);
            unsigned long long* dst = (unsigned long long*)
                (prec16 + ((size_t)(s0 + ss) * SEQL + t) * DIM + d0 + gq * 4);
            __hip_atomic_store(dst, vv, __ATOMIC_RELAXED,
                               __HIP_MEMORY_SCOPE_AGENT);
        }
    }
}

// ---------------- K7: pipelined LDS-staged MFMA logits (unchanged r2) ---------
__global__ __launch_bounds__(256, 2) void logits_mfma(
    const ushort* __restrict__ prec16, const ushort* __restrict__ score16,
    const float* __restrict__ debias, const unsigned char* __restrict__ rejm,
    float* __restrict__ s_glob, float* __restrict__ label_glob)
{
    __shared__ ushort Bt[2][16 * 512];          // 2 x 16 KB
    __shared__ float dbs[816];
    __shared__ unsigned char rjs[816];

    int bi = blockIdx.x;
    int i  = bi >> 3;
    int cs = (bi >> 1) & 3;
    int h  = bi & 1;
    int tile0  = cs * 101 + h * 51;             // global column-tile index base
    int ntiles = 51 - h;                        // 51 or 50
    int tid  = threadIdx.x;
    int lane = tid & 63;
    int w    = tid >> 6;
    int l15  = lane & 15, quad = lane >> 4;

    bf16x8 afrag[2][16];
    bool live1 = (w < 3);                       // row-tile 7 skipped
    {
        int r0 = i * SEQL + (2 * w) * 16 + l15;
        const ushort* ap = prec16 + (size_t)r0 * DIM + quad * 8;
#pragma unroll
        for (int c = 0; c < 16; ++c) afrag[0][c] = *(const bf16x8*)(ap + c * 32);
    }
    if (live1) {
        int r1 = i * SEQL + (2 * w + 1) * 16 + l15;
        const ushort* ap = prec16 + (size_t)r1 * DIM + quad * 8;
#pragma unroll
        for (int c = 0; c < 16; ++c) afrag[1][c] = *(const bf16x8*)(ap + c * 32);
    }

    int ncols = ntiles * 16;
    int nb0 = tile0 * 16;
    for (int idx = tid; idx < ncols; idx += 256) {
        dbs[idx] = debias[nb0 + idx];
        rjs[idx] = rejm[(size_t)i * NCOLS + nb0 + idx];
    }

    auto stage = [&](int buf, int st) {
        const char* slab = (const char*)(score16 + (size_t)(tile0 + st) * 16 * DIM);
#pragma unroll
        for (int k = 0; k < 4; ++k) {
            int o  = k * 4096 + w * 1024 + lane * 16;
            int so = o ^ (((o >> 10) & 15) << 4);
            __builtin_amdgcn_global_load_lds(
                (const __attribute__((address_space(1))) void*)(slab + so),
                (__attribute__((address_space(3))) void*)((char*)&Bt[buf][0] + k * 4096 + w * 1024),
                16, 0, 0);
        }
    };

    stage(0, 0);
    asm volatile("s_waitcnt vmcnt(0)" ::: "memory");
    __syncthreads();

    float srun0[4] = {0.f, 0.f, 0.f, 0.f};
    float srun1[4] = {0.f, 0.f, 0.f, 0.f};
    int colb = l15 * 1024;
    int q16  = quad * 16;
    int key  = l15 << 4;

    for (int st = 0; st < ntiles; ++st) {
        int cur = st & 1;
        if (st + 1 < ntiles) stage(cur ^ 1, st + 1);

        const char* bt = (const char*)&Bt[cur][0];
        f32x4 acc0[2] = {{0,0,0,0},{0,0,0,0}};
        f32x4 acc1[2] = {{0,0,0,0},{0,0,0,0}};
#pragma unroll
        for (int c = 0; c < 16; ++c) {
            int a = colb + ((c * 64 + q16) ^ key);
            bf16x8 b = *(const bf16x8*)(bt + a);
            acc0[c & 1] = __builtin_amdgcn_mfma_f32_16x16x32_bf16(afrag[0][c], b, acc0[c & 1], 0, 0, 0);
            if (live1)
                acc1[c & 1] = __builtin_amdgcn_mfma_f32_16x16x32_bf16(afrag[1][c], b, acc1[c & 1], 0, 0, 0);
        }

        int mi = st * 16 + l15;
        int n  = nb0 + mi;
        float db = dbs[mi];
        int   mc = rjs[mi];
        int   jj = n - i * L1P - 1;
        {
            int rowb = (2 * w) * 16 + quad * 4;
#pragma unroll
            for (int p = 0; p < 4; ++p) {
                int j = rowb + p;
                float l = acc0[0][p] + acc0[1][p] - db;
                bool is_t = (j == jj);
                bool msk = (mc == 1) || (mc == 2 && !is_t);
                l = msk ? MASKV : l;
                if (is_t && j < SEQL) label_glob[i * SEQL + j] = l;
                if (j < SEQL) srun0[p] += __expf(l - M0);
            }
        }
        if (live1) {
            int rowb = (2 * w + 1) * 16 + quad * 4;
#pragma unroll
            for (int p = 0; p < 4; ++p) {
                int j = rowb + p;
                float l = acc1[0][p] + acc1[1][p] - db;
                bool is_t = (j == jj);
                bool msk = (mc == 1) || (mc == 2 && !is_t);
                l = msk ? MASKV : l;
                if (is_t && j < SEQL) label_glob[i * SEQL + j] = l;
                if (j < SEQL) srun1[p] += __expf(l - M0);
            }
        }
        __syncthreads();
    }

#pragma unroll
    for (int p = 0; p < 4; ++p) {
        float s = srun0[p];
        s += __shfl_xor(s, 1); s += __shfl_xor(s, 2);
        s += __shfl_xor(s, 4); s += __shfl_xor(s, 8);
        if (l15 == 0) {
            int j = (2 * w) * 16 + quad * 4 + p;
            if (j < SEQL) atomicAdd(&s_glob[i * SEQL + j], s);
        }
    }
    if (live1) {
#pragma unroll
        for (int p = 0; p < 4; ++p) {
            float s = srun1[p];
            s += __shfl_xor(s, 1); s += __shfl_xor(s, 2);
            s += __shfl_xor(s, 4); s += __shfl_xor(s, 8);
            if (l15 == 0) {
                int j = (2 * w + 1) * 16 + quad * 4 + p;
                if (j < SEQL) atomicAdd(&s_glob[i * SEQL + j], s);
            }
        }
    }
}

// ---------------- K8: per-row NLL + weighted sum ------------------------------
__global__ void nll_reduce(const float* __restrict__ s_glob, const float* __restrict__ label_glob,
                           const int* __restrict__ lmask, float* __restrict__ acc)
{
    int r = blockIdx.x * 256 + threadIdx.x;
    float v = 0.f, wt = 0.f;
    if (r < NROWS) {
        wt = (lmask[r] != 0) ? 1.f : 0.f;
        v  = (M0 + __logf(s_glob[r]) - label_glob[r]) * wt;
    }
#pragma unroll
    for (int o = 32; o; o >>= 1) { v += __shfl_down(v, o); wt += __shfl_down(wt, o); }
    if ((threadIdx.x & 63) == 0) { atomicAdd(&acc[0], v); atomicAdd(&acc[1], wt); }
}

// ---------------- K9: finalize ------------------------------------------------
__global__ void finalize(const float* __restrict__ acc, float* __restrict__ out)
{
    out[0] = acc[0] / fmaxf(acc[1], 1.f);
}

extern "C" void kernel_launch(void* const* d_in, const int* in_sizes, int n_in,
                              void* d_out, int out_size, void* d_ws, size_t ws_size,
                              hipStream_t stream)
{
    const int*   ids   = (const int*)d_in[0];
    const int*   lmask = (const int*)d_in[1];
    const float* pop   = (const float*)d_in[2];
    const float* emb   = (const float*)d_in[3];
    const float* W_ih  = (const float*)d_in[4];
    const float* W_hh  = (const float*)d_in[5];
    const float* b_ih  = (const float*)d_in[6];
    const float* b_hh  = (const float*)d_in[7];
    float* out = (float*)d_out;

    // workspace layout (~57 MB)
    ushort* score16 = (ushort*)d_ws;                               // 6464*512 bf16
    ushort* prec16  = score16 + (size_t)NCOLS * DIM;               // 6416*512 bf16 (incl pad)
    ushort* WT      = prec16 + (size_t)(NROWS + 16) * DIM;         // 1536*512 bf16 (W_hh^T)
    ushort* WIT     = WT + (size_t)D3 * DIM;                       // 1536*512 bf16 (W_ih^T)
    float*  debias  = (float*)(WIT + (size_t)D3 * DIM);            // 6464 f32
    unsigned char* rejm = (unsigned char*)(debias + NCOLS);        // 64*6464 u8
    float*  gates   = (float*)(rejm + (size_t)BSZ * NCOLS + 64);   // 6400*1536 f32
    float*  s_glob  = gates + (size_t)NROWS * D3;                  // 6400 f32
    float*  label_g = s_glob + NROWS;                              // 6400 f32
    float*  acc     = label_g + NROWS;                             // 2 f32

    prologue<<<PB_TOTAL, 256, 0, stream>>>(ids, lmask, pop, emb, W_hh, W_ih,
                                           score16, (uint4*)prec16, WT, WIT,
                                           debias, rejm, s_glob, acc);
    gates_mfma<<<dim3(24, 10), 256, 0, stream>>>(score16, WIT, b_ih, gates);
    gru_mfma<<<GRU_BLOCKS, 256, 0, stream>>>(WT, b_hh, gates, prec16);
    logits_mfma<<<BSZ * 8, 256, 0, stream>>>(prec16, score16, debias, rejm, s_glob, label_g);
    nll_reduce<<<(NROWS + 255) / 256, 256, 0, stream>>>(s_glob, label_g, lmask, acc);
    finalize<<<1, 1, 0, stream>>>(acc, out);
}